// Round 6
// baseline (983.456 us; speedup 1.0000x reference)
//
#include <hip/hip_runtime.h>
#include <hip/hip_bf16.h>
#include <cstdint>

#define NV 3
#define NN 4096
#define HH 256
#define CC 20
#define DYY 300
#define DD 512

typedef __bf16 v8bf  __attribute__((ext_vector_type(8)));
typedef float  v16f  __attribute__((ext_vector_type(16)));

// Stage a 64x64 bf16 tile (8 KB, 512 chunks) via global_load_lds w=16.
// LDS dest linear (HW requirement); XOR swizzle (chunk ^= row&7) applied on
// the GLOBAL source side, matching XOR on ds_read (rule #21).
static __device__ __forceinline__ void stage_tile64(const __bf16* src, int strideElems,
                                                    char* lds, int tid)
{
#pragma unroll
    for (int i = 0; i < 2; ++i) {
        int id = i * 256 + tid;          // 16 B chunk id, 0..511
        int r = id >> 3, c = id & 7;
        const char* g = (const char*)(src + (size_t)r * strideElems)
                        + ((c ^ (r & 7)) << 4);
        __builtin_amdgcn_global_load_lds(
            (const __attribute__((address_space(1))) unsigned int*)g,
            (__attribute__((address_space(3))) unsigned int*)(lds + id * 16),
            16, 0, 0);
    }
}

static __device__ __forceinline__ v8bf frag_read(const char* lds, int ra, int q)
{
    return *(const v8bf*)(lds + ra * 128 + ((q ^ (ra & 7)) << 4));
}

// ---------------------------------------------------------------- k_yn
__global__ __launch_bounds__(256) void k_yn(
    const float* __restrict__ y, const float* __restrict__ Wy,
    const float* __restrict__ by, float* __restrict__ YN)
{
    __shared__ __align__(16) float ysh[DYY];
    int c = blockIdx.x, tid = threadIdx.x;
    for (int i = tid; i < DYY; i += 256) ysh[i] = y[c * DYY + i];
    __syncthreads();
    float acc = by[tid];
    const float4* Wr4 = (const float4*)(Wy + (size_t)tid * DYY);
    const float4* ys4 = (const float4*)ysh;
    for (int d4 = 0; d4 < DYY / 4; ++d4) {
        float4 w = Wr4[d4], yy = ys4[d4];
        acc = fmaf(yy.x, w.x, acc); acc = fmaf(yy.y, w.y, acc);
        acc = fmaf(yy.z, w.z, acc); acc = fmaf(yy.w, w.w, acc);
    }
    YN[c * HH + tid] = 1.0f / (1.0f + __expf(-acc));
}

// ---------------------------------------------------------------- k_proj
// R=32 rows/block (round-4 version, measured-good).
__global__ __launch_bounds__(256) void k_proj(
    const float* __restrict__ x0, const float* __restrict__ x1, const float* __restrict__ x2,
    const float* __restrict__ W0, const float* __restrict__ W1, const float* __restrict__ W2,
    const float* __restrict__ b0, const float* __restrict__ b1, const float* __restrict__ b2,
    const int* __restrict__ mask,
    float* __restrict__ XP, __hip_bfloat16* __restrict__ XQh,
    __hip_bfloat16* __restrict__ XPMT)
{
    const int R = 32;
    int tid = threadIdx.x;
    int blk = blockIdx.x;
    int v  = blk / (NN / R);
    int n0 = (blk % (NN / R)) * R;
    const float* xv = (v == 0) ? x0 : (v == 1 ? x1 : x2);
    const float* Wv = (v == 0) ? W0 : (v == 1 ? W1 : W2);
    const float* bv = (v == 0) ? b0 : (v == 1 ? b1 : b2);

    __shared__ __align__(16) float xsh[R][DD];     // 64 KB
    __shared__ float wred[4][R];
    __shared__ float nrm_sh[R];
    __shared__ int   msk_sh[R];

    const float4* xsrc = (const float4*)(xv + (size_t)n0 * DD);
    for (int i = tid; i < R * DD / 4; i += 256)
        ((float4*)xsh)[i] = xsrc[i];
    if (tid < R) msk_sh[tid] = mask[(n0 + tid) * NV + v];
    __syncthreads();

    float acc[R];
#pragma unroll
    for (int r = 0; r < R; ++r) acc[r] = 0.0f;
    const float4* Wrow = (const float4*)(Wv + (size_t)tid * DD);
#pragma unroll 2
    for (int d4 = 0; d4 < DD / 4; ++d4) {
        float4 w = Wrow[d4];
#pragma unroll
        for (int r = 0; r < R; ++r) {
            acc[r] = fmaf(xsh[r][4 * d4 + 0], w.x, acc[r]);
            acc[r] = fmaf(xsh[r][4 * d4 + 1], w.y, acc[r]);
            acc[r] = fmaf(xsh[r][4 * d4 + 2], w.z, acc[r]);
            acc[r] = fmaf(xsh[r][4 * d4 + 3], w.w, acc[r]);
        }
    }
    float bb = bv[tid];
    float vals[R];
#pragma unroll
    for (int r = 0; r < R; ++r) {
        float t = acc[r] + bb;
        vals[r] = (t >= 0.0f) ? t : 0.1f * t;
    }
    int lane = tid & 63, wv = tid >> 6;
#pragma unroll
    for (int r = 0; r < R; ++r) {
        float sq = vals[r] * vals[r];
#pragma unroll
        for (int off = 32; off > 0; off >>= 1)
            sq += __shfl_down(sq, off, 64);
        if (lane == 0) wred[wv][r] = sq;
    }
    __syncthreads();
    if (tid < R) {
        float s = wred[0][tid] + wred[1][tid] + wred[2][tid] + wred[3][tid];
        nrm_sh[tid] = fmaxf(sqrtf(s), 1e-12f);
    }
    __syncthreads();
#pragma unroll
    for (int r = 0; r < R; ++r) {
        size_t o = ((size_t)v * NN + n0 + r) * HH + tid;
        float xpv = vals[r];
        XP[o]  = xpv;
        XQh[o] = __float2bfloat16(xpv / nrm_sh[r]);
    }
#pragma unroll
    for (int g = 0; g < R / 8; ++g) {
        union { __hip_bfloat16 h[8]; uint4 u; } pk;
#pragma unroll
        for (int r = 0; r < 8; ++r)
            pk.h[r] = __float2bfloat16(msk_sh[g * 8 + r] ? vals[g * 8 + r] : 0.0f);
        *(uint4*)&XPMT[((size_t)v * HH + tid) * NN + n0 + g * 8] = pk.u;
    }
}

// ---------------------------------------------------------------- k_att
// Flash-fused: QK^T (3v) -> gate/max/exp -> {RS, CONF stats in-register}
// -> S@XPMT PV accumulate -> scale -> Z (and CONF from h0==0 slice).
// Block = 64 n-rows x 64 h-cols x all v; grid (NN/64, HH/64) = 256 blocks.
// Q resident in LDS (96 KB); K single-buffered per v (Ksh doubles as S-tile);
// Sb/RS/CM never touch global memory.
__global__ __launch_bounds__(256) void k_att(
    const __hip_bfloat16* __restrict__ XQh, const __hip_bfloat16* __restrict__ XPMT,
    const float* __restrict__ XP, const int* __restrict__ mask,
    const float* __restrict__ YN, float* __restrict__ Z, float* __restrict__ CONF)
{
    int n0 = blockIdx.x * 64, h0 = blockIdx.y * 64;
    bool doconf = (blockIdx.y == 0);
    int tid = threadIdx.x, lane = tid & 63, wid = tid >> 6;
    int wr = (wid >> 1) * 32, wc = (wid & 1) * 32;
    int rowA = lane & 31, hi = lane >> 5;

    __shared__ __align__(128) char Qsh[NV][4][8192];   // 96 KB, resident
    __shared__ __align__(128) char Ksh[4][8192];       // 32 KB, K tiles / S tile
    __shared__ __align__(128) char Psh[NV][8192];      // 24 KB, xp^T tiles
    __shared__ int mnsh[NV][64];
    __shared__ int mmsh[NV][64];
    __shared__ float rsum_lds[64];
    __shared__ unsigned int cmax_lds[NV][64];

    const __bf16* XQ = (const __bf16*)XQh;
    const __bf16* XM = (const __bf16*)XPMT;
    const size_t vstep = (size_t)NN * HH;

    // prologue: Q tiles + n-masks + reduction buffers
#pragma unroll
    for (int v = 0; v < NV; ++v)
#pragma unroll
        for (int kt = 0; kt < 4; ++kt)
            stage_tile64(XQ + (size_t)v * vstep + (size_t)n0 * HH + kt * 64,
                         HH, Qsh[v][kt], tid);
    if (tid < 64) {
        int mb = (n0 + tid) * NV;
        mnsh[0][tid] = mask[mb]; mnsh[1][tid] = mask[mb + 1]; mnsh[2][tid] = mask[mb + 2];
        rsum_lds[tid] = 0.0f;
        cmax_lds[0][tid] = 0u; cmax_lds[1][tid] = 0u; cmax_lds[2][tid] = 0u;
    }

    float rs[16];
#pragma unroll
    for (int r = 0; r < 16; ++r) rs[r] = 0.0f;
    float cmv[NV][16];
#pragma unroll
    for (int v = 0; v < NV; ++v)
#pragma unroll
        for (int r = 0; r < 16; ++r) cmv[v][r] = 0.0f;
    v16f pv[NV];
#pragma unroll
    for (int v = 0; v < NV; ++v) pv[v] = (v16f)0.0f;

#pragma unroll 1
    for (int mt = 0; mt < NN / 64; ++mt) {
        int m0 = mt * 64;
        __syncthreads();                 // prev PV done with Ksh(S)/Psh
        if (tid < 64) {
            int mb = (m0 + tid) * NV;
            mmsh[0][tid] = mask[mb]; mmsh[1][tid] = mask[mb + 1]; mmsh[2][tid] = mask[mb + 2];
        }
#pragma unroll
        for (int v = 0; v < NV; ++v)
            stage_tile64(XM + ((size_t)v * HH + h0) * NN + m0, NN, Psh[v], tid);
#pragma unroll
        for (int kt = 0; kt < 4; ++kt)
            stage_tile64(XQ + (size_t)m0 * HH + kt * 64, HH, Ksh[kt], tid);
        __syncthreads();                 // drain

        float comb[16];
#pragma unroll
        for (int r = 0; r < 16; ++r) comb[r] = -1e30f;

#pragma unroll 1
        for (int v = 0; v < NV; ++v) {
            v16f acc = (v16f)0.0f;
#pragma unroll
            for (int kt = 0; kt < 4; ++kt)
#pragma unroll
                for (int kk = 0; kk < 4; ++kk) {
                    int q = kk * 2 + hi;
                    v8bf a = frag_read(Qsh[v][kt], wr + rowA, q);
                    v8bf b = frag_read(Ksh[kt],   wc + rowA, q);
                    acc = __builtin_amdgcn_mfma_f32_32x32x16_bf16(a, b, acc, 0, 0, 0);
                }
            int cm_ = mmsh[v][wc + rowA];
#pragma unroll
            for (int r = 0; r < 16; ++r) {
                int rown = wr + (r & 3) + 8 * (r >> 2) + 4 * hi;
                float g = (cm_ && mnsh[v][rown]) ? acc[r] : -1e30f;
                comb[r] = fmaxf(comb[r], g);
            }
            if (v < NV - 1) {
                __syncthreads();         // all waves done reading Ksh for v
#pragma unroll
                for (int kt = 0; kt < 4; ++kt)
                    stage_tile64(XQ + (size_t)(v + 1) * vstep + (size_t)m0 * HH + kt * 64,
                                 HH, Ksh[kt], tid);
                __syncthreads();         // drain
            }
        }

        // S = exp(5*comb), zero diag; accumulate stats in-register
        int col = wc + rowA;
        bool dtile = (mt == blockIdx.x);
        float sv[16];
#pragma unroll
        for (int r = 0; r < 16; ++r) {
            int rown = wr + (r & 3) + 8 * (r >> 2) + 4 * hi;
            float e = __expf(comb[r] * 5.0f);
            if (dtile && rown == col) e = 0.0f;
            sv[r] = e;
            rs[r] += e;
        }
        if (doconf) {
#pragma unroll
            for (int v = 0; v < NV; ++v) {
                int g = mmsh[v][col];
#pragma unroll
                for (int r = 0; r < 16; ++r)
                    cmv[v][r] = fmaxf(cmv[v][r], g ? sv[r] : 0.0f);
            }
        }

        __syncthreads();                 // QK v2 reads of Ksh done -> reuse as S
        // write S tile (bf16, swizzled layout) into Ksh[0]
#pragma unroll
        for (int r = 0; r < 16; ++r) {
            int rown = wr + (r & 3) + 8 * (r >> 2) + 4 * hi;
            int byte = rown * 128 + ((((col) >> 3) ^ (rown & 7)) << 4) + ((col * 2) & 15);
            __hip_bfloat16 hb = __float2bfloat16(sv[r]);
            *(unsigned short*)((char*)Ksh + byte) = *(unsigned short*)&hb;
        }
        __syncthreads();

        // PV: pv[v] += S @ xpT[v]
#pragma unroll
        for (int v = 0; v < NV; ++v)
#pragma unroll
            for (int kk = 0; kk < 4; ++kk) {
                int q = kk * 2 + hi;
                v8bf a = frag_read((char*)Ksh, wr + rowA, q);
                v8bf b = frag_read(Psh[v],     wc + rowA, q);
                pv[v] = __builtin_amdgcn_mfma_f32_32x32x16_bf16(a, b, pv[v], 0, 0, 0);
            }
    }

    // ---- epilogue: reduce RS (and CM) across lanes, then scale + write Z
#pragma unroll
    for (int r = 0; r < 16; ++r) {
        float x = rs[r];
#pragma unroll
        for (int off = 16; off > 0; off >>= 1)
            x += __shfl_xor(x, off, 64);
        if (rowA == 0) {
            int rown = wr + (r & 3) + 8 * (r >> 2) + 4 * hi;
            atomicAdd(&rsum_lds[rown], x);
        }
    }
    if (doconf) {
#pragma unroll
        for (int v = 0; v < NV; ++v)
#pragma unroll
            for (int r = 0; r < 16; ++r) {
                float x = cmv[v][r];
#pragma unroll
                for (int off = 16; off > 0; off >>= 1)
                    x = fmaxf(x, __shfl_xor(x, off, 64));
                if (rowA == 0) {
                    int rown = wr + (r & 3) + 8 * (r >> 2) + 4 * hi;
                    atomicMax(&cmax_lds[v][rown], __float_as_uint(x));
                }
            }
    }
    __syncthreads();

    int h = h0 + wc + rowA;
#pragma unroll 1
    for (int v = 0; v < NV; ++v) {
        float val[16];
        size_t rb[16];
#pragma unroll
        for (int r = 0; r < 16; ++r) {
            int rown = wr + (r & 3) + 8 * (r >> 2) + 4 * hi;
            float rsn = 1.0f / (rsum_lds[rown] + 1e-9f);
            size_t o = ((size_t)v * NN + n0 + rown) * HH + h;
            val[r] = mnsh[v][rown] ? XP[o] : pv[v][r] * rsn;
            rb[r]  = ((size_t)v * NN + n0 + rown) * CC * HH + h;
        }
#pragma unroll 1
        for (int c = 0; c < CC; ++c) {
            float ynv = YN[c * HH + h];
#pragma unroll
            for (int r = 0; r < 16; ++r)
                Z[rb[r] + (size_t)c * HH] = val[r] * ynv;
        }
    }

    if (doconf && tid < 64) {
#pragma unroll
        for (int v = 0; v < NV; ++v) {
            float cm = __uint_as_float(cmax_lds[v][tid]);
            float lg = 0.2f * __logf(cm + 1e-9f);
            CONF[(size_t)v * NN + n0 + tid] = fminf(fmaxf(lg, 0.0f), 1.0f);
        }
    }
}

// ---------------------------------------------------------------- launch
extern "C" void kernel_launch(void* const* d_in, const int* in_sizes, int n_in,
                              void* d_out, int out_size, void* d_ws, size_t ws_size,
                              hipStream_t stream)
{
    (void)in_sizes; (void)n_in; (void)out_size; (void)ws_size;
    const float* x0 = (const float*)d_in[0];
    const float* W0 = (const float*)d_in[1];
    const float* b0 = (const float*)d_in[2];
    const float* x1 = (const float*)d_in[3];
    const float* W1 = (const float*)d_in[4];
    const float* b1 = (const float*)d_in[5];
    const float* x2 = (const float*)d_in[6];
    const float* W2 = (const float*)d_in[7];
    const float* b2 = (const float*)d_in[8];
    const float* y  = (const float*)d_in[9];
    const float* Wy = (const float*)d_in[10];
    const float* by = (const float*)d_in[11];
    const int* mask = (const int*)d_in[12];
    float* out = (float*)d_out;
    float* CONF = out + (size_t)NV * NN * CC * HH;

    // ws layout (bytes) — 25.25 MB total (harness grants >= 58.9 MB, measured r1/r3):
    //   XPMT bf16 V*H*N @ 0          6,291,456
    //   XQh  bf16 V*N*H @ 6291456    6,291,456
    //   XP   f32  V*N*H @ 12582912  12,582,912
    //   YN   f32  C*H   @ 25165824      81,920
    char* w = (char*)d_ws;
    __hip_bfloat16* XPMT = (__hip_bfloat16*)w;
    __hip_bfloat16* XQh  = (__hip_bfloat16*)(w + 6291456);
    float*          XP   = (float*)(w + 12582912);
    float*          YN   = (float*)(w + 25165824);

    k_yn<<<CC, 256, 0, stream>>>(y, Wy, by, YN);
    k_proj<<<NV * NN / 32, 256, 0, stream>>>(x0, x1, x2, W0, W1, W2,
                                             b0, b1, b2, mask, XP, XQh, XPMT);
    dim3 ga(NN / 64, HH / 64);
    k_att<<<ga, 256, 0, stream>>>(XQh, XPMT, XP, mask, YN, out, CONF);
}